// Round 6
// baseline (276.493 us; speedup 1.0000x reference)
//
#include <hip/hip_runtime.h>
#include <cstddef>

#define BB 8
#define CC 512
#define LL 2048
#define TT 64

typedef short short8 __attribute__((ext_vector_type(8)));
typedef float floatx4 __attribute__((ext_vector_type(4)));
typedef unsigned short b16u;

static __device__ __forceinline__ unsigned f2bfu(float f) {
    unsigned u = __float_as_uint(f);
    u += 0x7fffu + ((u >> 16) & 1u);          // round-to-nearest-even
    return u >> 16;
}
static __device__ __forceinline__ float bfu2f(unsigned h) {
    return __uint_as_float(h << 16);
}

#define MFMA16(a, b, c) __builtin_amdgcn_mfma_f32_16x16x32_bf16((a), (b), (c), 0, 0, 0)

// ---------------------------------------------------------------------------
// K0: W1,W2 (64x512 fp32) -> bf16 hi/lo split, row-major.
// ---------------------------------------------------------------------------
__global__ __launch_bounds__(256) void wcvt_kernel(
    const float* __restrict__ W1, const float* __restrict__ W2,
    b16u* __restrict__ W1h, b16u* __restrict__ W1l,
    b16u* __restrict__ W2h, b16u* __restrict__ W2l)
{
    int flat = blockIdx.x * 256 + threadIdx.x;        // 0..8191 float4 groups
    float4 v1 = *(const float4*)(W1 + (size_t)flat * 4);
    float4 v2 = *(const float4*)(W2 + (size_t)flat * 4);
    const float* e1 = (const float*)&v1;
    const float* e2 = (const float*)&v2;
    unsigned h1[4], l1[4], h2[4], l2[4];
#pragma unroll
    for (int k = 0; k < 4; ++k) {
        h1[k] = f2bfu(e1[k]); l1[k] = f2bfu(e1[k] - bfu2f(h1[k]));
        h2[k] = f2bfu(e2[k]); l2[k] = f2bfu(e2[k] - bfu2f(h2[k]));
    }
    uint2 a, b, c, d;
    a.x = h1[0] | (h1[1] << 16); a.y = h1[2] | (h1[3] << 16);
    b.x = l1[0] | (l1[1] << 16); b.y = l1[2] | (l1[3] << 16);
    c.x = h2[0] | (h2[1] << 16); c.y = h2[2] | (h2[3] << 16);
    d.x = l2[0] | (l2[1] << 16); d.y = l2[2] | (l2[3] << 16);
    *(uint2*)(W1h + (size_t)flat * 4) = a;
    *(uint2*)(W1l + (size_t)flat * 4) = b;
    *(uint2*)(W2h + (size_t)flat * 4) = c;
    *(uint2*)(W2l + (size_t)flat * 4) = d;
}

// ---------------------------------------------------------------------------
// K1: merged cvt+qk. Reads x once, transposes 64x64 chunks hi/lo in LDS,
// computes Q = W1@X, K = W2@X via split-bf16 MFMA (hh+hl+lh).
// -> Qt/Kt (b, l, 64t) bf16.  grid (32 l-tiles, 8 b), block 256.
// ---------------------------------------------------------------------------
__global__ __launch_bounds__(256) void qkcvt_kernel(
    const float* __restrict__ x,
    const b16u* __restrict__ W1h, const b16u* __restrict__ W1l,
    const b16u* __restrict__ W2h, const b16u* __restrict__ W2l,
    b16u* __restrict__ Qt, b16u* __restrict__ Kt)
{
    __shared__ b16u Sxh[64 * 72];   // [l][c-chunk]
    __shared__ b16u Sxl[64 * 72];
    __shared__ b16u S1h[64 * 72];   // [t][c-chunk]
    __shared__ b16u S1l[64 * 72];
    __shared__ b16u S2h[64 * 72];
    __shared__ b16u S2l[64 * 72];
    const int b  = blockIdx.y;
    const int l0 = blockIdx.x * 64;
    const int tid = threadIdx.x;
    const int lane = tid & 63;
    const int w = tid >> 6;
    const int n16 = lane & 15;
    const int q = lane >> 4;
    const float* xb = x + (size_t)b * CC * LL;

    const int cx = tid >> 2;            // 0..63: c row within chunk (x load)
    const int sx = tid & 3;             // float4 group base; covers 16 l via 4 passes

    float4 xreg[4];
#pragma unroll
    for (int p = 0; p < 4; ++p)         // chunk 0: c = cx, l-group = sx*4 + p? no:
        xreg[p] = *(const float4*)(xb + (size_t)cx * LL + l0 + (sx * 4 + p) * 4);

    floatx4 aq[4], ak[4];
#pragma unroll
    for (int nt = 0; nt < 4; ++nt) {
        aq[nt] = (floatx4){0.f, 0.f, 0.f, 0.f};
        ak[nt] = (floatx4){0.f, 0.f, 0.f, 0.f};
    }

    for (int c0 = 0; c0 < 512; c0 += 64) {
        __syncthreads();                // prev MFMA reads done
        // scatter hi/lo transposed: Sx[l][c]
#pragma unroll
        for (int p = 0; p < 4; ++p) {
            const float* e = (const float*)&xreg[p];
            int lbase = (sx * 4 + p) * 4;
#pragma unroll
            for (int k = 0; k < 4; ++k) {
                unsigned h = f2bfu(e[k]);
                unsigned lo = f2bfu(e[k] - bfu2f(h));
                Sxh[(lbase + k) * 72 + cx] = (b16u)h;
                Sxl[(lbase + k) * 72 + cx] = (b16u)lo;
            }
        }
        // stage W tiles [t][c-chunk]
#pragma unroll
        for (int p = 0; p < 2; ++p) {
            int flat = tid + p * 256;   // 0..511: t = flat>>3, s8 = flat&7
            int t = flat >> 3, s8 = flat & 7;
            size_t off = (size_t)t * 512 + c0 + s8 * 8;
            *(uint4*)&S1h[t * 72 + s8 * 8] = *(const uint4*)(W1h + off);
            *(uint4*)&S1l[t * 72 + s8 * 8] = *(const uint4*)(W1l + off);
            *(uint4*)&S2h[t * 72 + s8 * 8] = *(const uint4*)(W2h + off);
            *(uint4*)&S2l[t * 72 + s8 * 8] = *(const uint4*)(W2l + off);
        }
        __syncthreads();
        // prefetch next x chunk
        if (c0 < 448) {
#pragma unroll
            for (int p = 0; p < 4; ++p)
                xreg[p] = *(const float4*)(xb + (size_t)(c0 + 64 + cx) * LL +
                                           l0 + (sx * 4 + p) * 4);
        }
        // MFMA: 6-term split accumulate
#pragma unroll
        for (int kc = 0; kc < 2; ++kc) {
            const int ao = (w * 16 + n16) * 72 + kc * 32 + q * 8;
            short8 a1h = *(const short8*)&S1h[ao];
            short8 a1l = *(const short8*)&S1l[ao];
            short8 a2h = *(const short8*)&S2h[ao];
            short8 a2l = *(const short8*)&S2l[ao];
#pragma unroll
            for (int nt = 0; nt < 4; ++nt) {
                const int bo = (nt * 16 + n16) * 72 + kc * 32 + q * 8;
                short8 bh = *(const short8*)&Sxh[bo];
                short8 bl = *(const short8*)&Sxl[bo];
                aq[nt] = MFMA16(a1h, bh, aq[nt]);
                aq[nt] = MFMA16(a1h, bl, aq[nt]);
                aq[nt] = MFMA16(a1l, bh, aq[nt]);
                ak[nt] = MFMA16(a2h, bh, ak[nt]);
                ak[nt] = MFMA16(a2h, bl, ak[nt]);
                ak[nt] = MFMA16(a2l, bh, ak[nt]);
            }
        }
    }
    // C/D: col = n16 = l within n-tile, row = q*4+r = t within m-tile
#pragma unroll
    for (int nt = 0; nt < 4; ++nt) {
        int l = l0 + nt * 16 + n16;
        uint2 pq, pk;
        pq.x = f2bfu(aq[nt][0]) | (f2bfu(aq[nt][1]) << 16);
        pq.y = f2bfu(aq[nt][2]) | (f2bfu(aq[nt][3]) << 16);
        pk.x = f2bfu(ak[nt][0]) | (f2bfu(ak[nt][1]) << 16);
        pk.y = f2bfu(ak[nt][2]) | (f2bfu(ak[nt][3]) << 16);
        *(uint2*)(Qt + ((size_t)(b * 2048) + l) * 64 + w * 16 + q * 4) = pq;
        *(uint2*)(Kt + ((size_t)(b * 2048) + l) * 64 + w * 16 + q * 4) = pk;
    }
}

// ---------------------------------------------------------------------------
// K2: P[pb, j, i] = bf16(exp(S[j,i] - 20)), Zpart[ih, b, j] = partial row sums.
// grid (2 i-halves, 32 j-tiles, nb batches), block 256 (wave w: 16 j rows).
// S orientation MFMA (A=Q, B=K): lane col=n16=i, row=q*4+r=j. P staged through
// Ls (stride 76: disjoint-bank u16 writes) then written coalesced.
// ---------------------------------------------------------------------------
__global__ __launch_bounds__(256) void pexp_kernel(
    const b16u* __restrict__ Qt, const b16u* __restrict__ Kt,
    b16u* __restrict__ P, float* __restrict__ Zpart, int b_off)
{
    __shared__ b16u Ks[64 * 72];    // [i][t]
    __shared__ b16u Ls[64 * 76];    // [j][i] staging
    const int pb = blockIdx.z, b = b_off + pb;
    const int j0 = blockIdx.y * 64;
    const int ibase = blockIdx.x * 1024;
    const int tid = threadIdx.x;
    const int lane = tid & 63;
    const int w = tid >> 6;
    const int n16 = lane & 15;
    const int q = lane >> 4;
    const b16u* kb = Kt + (size_t)b * (2048 * 64);

    short8 qf[2];
#pragma unroll
    for (int kc = 0; kc < 2; ++kc)
        qf[kc] = *(const short8*)(Qt +
            ((size_t)(b * 2048) + j0 + w * 16 + n16) * 64 + kc * 32 + q * 8);

    uint4 kreg[2];
#pragma unroll
    for (int p = 0; p < 2; ++p) {
        int flat = tid + p * 256;
        kreg[p] = *(const uint4*)(kb + (size_t)(ibase + (flat >> 3)) * 64 + (flat & 7) * 8);
    }
    float zp[4] = {0.f, 0.f, 0.f, 0.f};

    for (int it = 0; it < 16; ++it) {
#pragma unroll
        for (int p = 0; p < 2; ++p) {
            int flat = tid + p * 256;
            *(uint4*)&Ks[(flat >> 3) * 72 + (flat & 7) * 8] = kreg[p];
        }
        {
            const int itn = (it + 1 < 16) ? it + 1 : 15;
#pragma unroll
            for (int p = 0; p < 2; ++p) {
                int flat = tid + p * 256;
                kreg[p] = *(const uint4*)(kb +
                    (size_t)(ibase + itn * 64 + (flat >> 3)) * 64 + (flat & 7) * 8);
            }
        }
        __syncthreads();
        floatx4 sacc[4];
#pragma unroll
        for (int ns = 0; ns < 4; ++ns) sacc[ns] = (floatx4){0.f, 0.f, 0.f, 0.f};
#pragma unroll
        for (int kc = 0; kc < 2; ++kc)
#pragma unroll
            for (int ns = 0; ns < 4; ++ns) {
                short8 kf = *(const short8*)&Ks[(ns * 16 + n16) * 72 + kc * 32 + q * 8];
                sacc[ns] = MFMA16(qf[kc], kf, sacc[ns]);
            }
#pragma unroll
        for (int ns = 0; ns < 4; ++ns)
#pragma unroll
            for (int r = 0; r < 4; ++r) {
                float p = __expf(sacc[ns][r] - 20.0f);
                zp[r] += p;
                Ls[(w * 16 + q * 4 + r) * 76 + ns * 16 + n16] = (b16u)f2bfu(p);
            }
        __syncthreads();
        // coalesced P write: 64 rows x 64 i
        size_t prow = ((size_t)(pb * 2048) + j0) * 2048 + ibase + it * 64;
#pragma unroll
        for (int p = 0; p < 4; ++p) {
            int flat = tid + p * 256;
            int row = flat >> 4, s = flat & 15;
            *(uint2*)(P + prow + (size_t)row * 2048 + s * 4) =
                *(const uint2*)&Ls[row * 76 + s * 4];
        }
    }
#pragma unroll
    for (int r = 0; r < 4; ++r) {
        float zv = zp[r];
#pragma unroll
        for (int off = 1; off < 16; off <<= 1) zv += __shfl_xor(zv, off);
        if (n16 == 0)
            Zpart[((size_t)blockIdx.x * 8 + b) * 2048 + j0 + w * 16 + q * 4 + r] = zv;
    }
}

// ---------------------------------------------------------------------------
// K3: out[b,c,j] = x[b,c,j] + g * zinv[j] * sum_i bf16(x[b,c,i]) * P[j,i]
// Clean GEMM: M=512(c) N=2048(j) K=2048(i), 128x128 block tile, BK=64,
// double-buffered LDS + register prefetch, ONE barrier per iter.
// grid (16 j, 4 c, nb), block 256; wave = 64c x 64j quadrant.
// ---------------------------------------------------------------------------
__global__ __launch_bounds__(256, 2) void gemm_kernel(
    const float* __restrict__ x, const b16u* __restrict__ P,
    const float* __restrict__ Zpart, const float* __restrict__ gamma,
    float* __restrict__ out, int b_off)
{
    __shared__ b16u As[2][128 * 72];   // [c][i] bf16
    __shared__ b16u Bs[2][128 * 72];   // [j][i]
    const int pb = blockIdx.z, b = b_off + pb;
    const int j0 = blockIdx.x * 128;
    const int c0 = blockIdx.y * 128;
    const int tid = threadIdx.x;
    const int lane = tid & 63;
    const int w = tid >> 6;
    const int n16 = lane & 15;
    const int q = lane >> 4;
    const int wc = w & 1;              // c-half
    const int wj = w >> 1;             // j-half
    const float* xb = x + (size_t)b * CC * LL;
    const b16u* Pb = P + (size_t)pb * 2048 * 2048;
    const int ra = tid >> 1;           // A-stage: row c (0..127)
    const int sa = tid & 1;            // 32-float half-row base
    const int rb = tid >> 1;           // B-stage: row j
    const int sb = tid & 1;

    float4 ar[8];
    uint4 br[4];
    // A: thread covers rows ra, 32 i's at sa*32 (8 floats x 4 groups)
#define LOADA(IT)                                                         \
    {                                                                      \
        const float* src = xb + (size_t)(c0 + ra) * LL + (IT) * 64 + sa * 32; \
        _Pragma("unroll")                                                  \
        for (int p = 0; p < 4; ++p) {                                      \
            ar[2 * p]     = *(const float4*)(src + p * 8);                 \
            ar[2 * p + 1] = *(const float4*)(src + p * 8 + 4);             \
        }                                                                  \
    }
#define LOADB(IT)                                                         \
    {                                                                      \
        const b16u* src = Pb + (size_t)(j0 + rb) * 2048 + (IT) * 64 + sb * 32; \
        _Pragma("unroll")                                                  \
        for (int p = 0; p < 4; ++p)                                        \
            br[p] = *(const uint4*)(src + p * 8);                          \
    }
#define STOREAB(BUF)                                                      \
    {                                                                      \
        _Pragma("unroll")                                                  \
        for (int p = 0; p < 4; ++p) {                                      \
            const float* e0 = (const float*)&ar[2 * p];                    \
            const float* e1 = (const float*)&ar[2 * p + 1];                \
            uint4 w4;                                                      \
            w4.x = f2bfu(e0[0]) | (f2bfu(e0[1]) << 16);                    \
            w4.y = f2bfu(e0[2]) | (f2bfu(e0[3]) << 16);                    \
            w4.z = f2bfu(e1[0]) | (f2bfu(e1[1]) << 16);                    \
            w4.w = f2bfu(e1[2]) | (f2bfu(e1[3]) << 16);                    \
            *(uint4*)&As[BUF][ra * 72 + sa * 32 + p * 8] = w4;             \
            *(uint4*)&Bs[BUF][rb * 72 + sb * 32 + p * 8] = br[p];          \
        }                                                                  \
    }

    LOADA(0) LOADB(0)
    STOREAB(0)
    LOADA(1) LOADB(1)
    __syncthreads();

    floatx4 acc[4][4];
#pragma unroll
    for (int mt = 0; mt < 4; ++mt)
#pragma unroll
        for (int nt = 0; nt < 4; ++nt) acc[mt][nt] = (floatx4){0.f, 0.f, 0.f, 0.f};

    for (int it = 0; it < 32; ++it) {
        const int cur = it & 1;
#pragma unroll
        for (int kc = 0; kc < 2; ++kc) {
            short8 af[4], bf4[4];
#pragma unroll
            for (int mt = 0; mt < 4; ++mt)
                af[mt] = *(const short8*)&As[cur][(wc * 64 + mt * 16 + n16) * 72 + kc * 32 + q * 8];
#pragma unroll
            for (int nt = 0; nt < 4; ++nt)
                bf4[nt] = *(const short8*)&Bs[cur][(wj * 64 + nt * 16 + n16) * 72 + kc * 32 + q * 8];
#pragma unroll
            for (int mt = 0; mt < 4; ++mt)
#pragma unroll
                for (int nt = 0; nt < 4; ++nt)
                    acc[mt][nt] = MFMA16(af[mt], bf4[nt], acc[mt][nt]);
        }
        if (it < 31) {
            STOREAB(cur ^ 1)                       // tile it+1 from regs
            const int itn = (it + 2 < 32) ? it + 2 : 31;
            LOADA(itn) LOADB(itn)                  // tile it+2 into regs
        }
        __syncthreads();
    }

    // epilogue: zinv from the two i-half partials, residual, store
    const float g = gamma[0];
#pragma unroll
    for (int nt = 0; nt < 4; ++nt) {
        int j = j0 + wj * 64 + nt * 16 + n16;
        float zi = 1.0f / (Zpart[(size_t)b * 2048 + j] +
                           Zpart[(size_t)(8 * 2048) + (size_t)b * 2048 + j]);
#pragma unroll
        for (int mt = 0; mt < 4; ++mt) {
            int c = c0 + wc * 64 + mt * 16 + q * 4;
#pragma unroll
            for (int r = 0; r < 4; ++r) {
                size_t go = ((size_t)(b * 512) + c + r) * 2048 + j;
                out[go] = x[go] + g * acc[mt][nt][r] * zi;
            }
        }
    }
#undef LOADA
#undef LOADB
#undef STOREAB
}

// ---------------------------------------------------------------------------
extern "C" void kernel_launch(void* const* d_in, const int* in_sizes, int n_in,
                              void* d_out, int out_size, void* d_ws, size_t ws_size,
                              hipStream_t stream)
{
    const float* x     = (const float*)d_in[0];
    const float* W1    = (const float*)d_in[1];
    const float* W2    = (const float*)d_in[2];
    const float* gamma = (const float*)d_in[3];
    float* out = (float*)d_out;

    b16u* Qt  = (b16u*)d_ws;                        // 2 MB
    b16u* Kt  = Qt  + (size_t)BB * LL * TT;         // 2 MB
    b16u* W1h = Kt  + (size_t)BB * LL * TT;         // 64 KB x4
    b16u* W1l = W1h + (size_t)TT * CC;
    b16u* W2h = W1l + (size_t)TT * CC;
    b16u* W2l = W2h + (size_t)TT * CC;
    float* Zp = (float*)(W2l + (size_t)TT * CC);    // 2*8*2048 floats = 128 KB
    b16u* P   = (b16u*)(Zp + 2 * 8 * 2048);         // nb * 8.4 MB

    const size_t base  = ((char*)P - (char*)d_ws);  // ~4.6 MB
    const size_t pbat  = (size_t)LL * LL * 2;       // 8.39 MB per batch
    int nb = 8;
    if (ws_size < base + 8 * pbat) nb = 4;
    if (ws_size < base + 4 * pbat) nb = 2;
    if (ws_size < base + 2 * pbat) nb = 1;

    wcvt_kernel <<<dim3(32),        256, 0, stream>>>(W1, W2, W1h, W1l, W2h, W2l);
    qkcvt_kernel<<<dim3(32, BB),    256, 0, stream>>>(x, W1h, W1l, W2h, W2l, Qt, Kt);
    for (int b0 = 0; b0 < BB; b0 += nb) {
        pexp_kernel<<<dim3(2, 32, nb), 256, 0, stream>>>(Qt, Kt, P, Zp, b0);
        gemm_kernel<<<dim3(16, 4, nb), 256, 0, stream>>>(x, P, Zp, gamma, out, b0);
    }
}

// Round 7
// 172.127 us; speedup vs baseline: 1.6063x; 1.6063x over previous
//
#include <hip/hip_runtime.h>
#include <cstddef>

#define BB 8
#define CC 512
#define LL 2048
#define TT 64

typedef short short8 __attribute__((ext_vector_type(8)));
typedef float floatx4 __attribute__((ext_vector_type(4)));
typedef unsigned short b16u;
typedef unsigned int u32;

static __device__ __forceinline__ unsigned f2bfu(float f) {
    unsigned u = __float_as_uint(f);
    u += 0x7fffu + ((u >> 16) & 1u);          // round-to-nearest-even
    return u >> 16;
}
static __device__ __forceinline__ float bfu2f(unsigned h) {
    return __uint_as_float(h << 16);
}

#define MFMA16(a, b, c) __builtin_amdgcn_mfma_f32_16x16x32_bf16((a), (b), (c), 0, 0, 0)

// async 16B global->LDS (DMA, no VGPR round trip). LDS dest must be
// wave-uniform base; HW adds lane*16.
static __device__ __forceinline__ void gl2lds16(const void* g, void* l) {
    __builtin_amdgcn_global_load_lds(
        (const __attribute__((address_space(1))) u32*)g,
        (__attribute__((address_space(3))) u32*)l, 16, 0, 0);
}

// ---------------------------------------------------------------------------
// K0: W1,W2 (64x512 fp32) -> bf16 hi/lo split, row-major.
// ---------------------------------------------------------------------------
__global__ __launch_bounds__(256) void wcvt_kernel(
    const float* __restrict__ W1, const float* __restrict__ W2,
    b16u* __restrict__ W1h, b16u* __restrict__ W1l,
    b16u* __restrict__ W2h, b16u* __restrict__ W2l)
{
    int flat = blockIdx.x * 256 + threadIdx.x;        // 0..8191 float4 groups
    float4 v1 = *(const float4*)(W1 + (size_t)flat * 4);
    float4 v2 = *(const float4*)(W2 + (size_t)flat * 4);
    const float* e1 = (const float*)&v1;
    const float* e2 = (const float*)&v2;
    unsigned h1[4], l1[4], h2[4], l2[4];
#pragma unroll
    for (int k = 0; k < 4; ++k) {
        h1[k] = f2bfu(e1[k]); l1[k] = f2bfu(e1[k] - bfu2f(h1[k]));
        h2[k] = f2bfu(e2[k]); l2[k] = f2bfu(e2[k] - bfu2f(h2[k]));
    }
    uint2 a, b, c, d;
    a.x = h1[0] | (h1[1] << 16); a.y = h1[2] | (h1[3] << 16);
    b.x = l1[0] | (l1[1] << 16); b.y = l1[2] | (l1[3] << 16);
    c.x = h2[0] | (h2[1] << 16); c.y = h2[2] | (h2[3] << 16);
    d.x = l2[0] | (l2[1] << 16); d.y = l2[2] | (l2[3] << 16);
    *(uint2*)(W1h + (size_t)flat * 4) = a;
    *(uint2*)(W1l + (size_t)flat * 4) = b;
    *(uint2*)(W2h + (size_t)flat * 4) = c;
    *(uint2*)(W2l + (size_t)flat * 4) = d;
}

// ---------------------------------------------------------------------------
// K1: merged cvt+qk (unchanged from R6): Q = W1@X, K = W2@X via split-bf16
// MFMA (hh+hl+lh) -> Qt/Kt (b, l, 64t) bf16.  grid (32 l-tiles, 8 b).
// ---------------------------------------------------------------------------
__global__ __launch_bounds__(256) void qkcvt_kernel(
    const float* __restrict__ x,
    const b16u* __restrict__ W1h, const b16u* __restrict__ W1l,
    const b16u* __restrict__ W2h, const b16u* __restrict__ W2l,
    b16u* __restrict__ Qt, b16u* __restrict__ Kt)
{
    __shared__ b16u Sxh[64 * 72];   // [l][c-chunk]
    __shared__ b16u Sxl[64 * 72];
    __shared__ b16u S1h[64 * 72];   // [t][c-chunk]
    __shared__ b16u S1l[64 * 72];
    __shared__ b16u S2h[64 * 72];
    __shared__ b16u S2l[64 * 72];
    const int b  = blockIdx.y;
    const int l0 = blockIdx.x * 64;
    const int tid = threadIdx.x;
    const int lane = tid & 63;
    const int w = tid >> 6;
    const int n16 = lane & 15;
    const int qd = lane >> 4;
    const float* xb = x + (size_t)b * CC * LL;

    const int cx = tid >> 2;
    const int sx = tid & 3;

    float4 xreg[4];
#pragma unroll
    for (int p = 0; p < 4; ++p)
        xreg[p] = *(const float4*)(xb + (size_t)cx * LL + l0 + (sx * 4 + p) * 4);

    floatx4 aq[4], ak[4];
#pragma unroll
    for (int nt = 0; nt < 4; ++nt) {
        aq[nt] = (floatx4){0.f, 0.f, 0.f, 0.f};
        ak[nt] = (floatx4){0.f, 0.f, 0.f, 0.f};
    }

    for (int c0 = 0; c0 < 512; c0 += 64) {
        __syncthreads();
#pragma unroll
        for (int p = 0; p < 4; ++p) {
            const float* e = (const float*)&xreg[p];
            int lbase = (sx * 4 + p) * 4;
#pragma unroll
            for (int k = 0; k < 4; ++k) {
                unsigned h = f2bfu(e[k]);
                unsigned lo = f2bfu(e[k] - bfu2f(h));
                Sxh[(lbase + k) * 72 + cx] = (b16u)h;
                Sxl[(lbase + k) * 72 + cx] = (b16u)lo;
            }
        }
#pragma unroll
        for (int p = 0; p < 2; ++p) {
            int flat = tid + p * 256;
            int t = flat >> 3, s8 = flat & 7;
            size_t off = (size_t)t * 512 + c0 + s8 * 8;
            *(uint4*)&S1h[t * 72 + s8 * 8] = *(const uint4*)(W1h + off);
            *(uint4*)&S1l[t * 72 + s8 * 8] = *(const uint4*)(W1l + off);
            *(uint4*)&S2h[t * 72 + s8 * 8] = *(const uint4*)(W2h + off);
            *(uint4*)&S2l[t * 72 + s8 * 8] = *(const uint4*)(W2l + off);
        }
        __syncthreads();
        if (c0 < 448) {
#pragma unroll
            for (int p = 0; p < 4; ++p)
                xreg[p] = *(const float4*)(xb + (size_t)(c0 + 64 + cx) * LL +
                                           l0 + (sx * 4 + p) * 4);
        }
#pragma unroll
        for (int kc = 0; kc < 2; ++kc) {
            const int ao = (w * 16 + n16) * 72 + kc * 32 + qd * 8;
            short8 a1h = *(const short8*)&S1h[ao];
            short8 a1l = *(const short8*)&S1l[ao];
            short8 a2h = *(const short8*)&S2h[ao];
            short8 a2l = *(const short8*)&S2l[ao];
#pragma unroll
            for (int nt = 0; nt < 4; ++nt) {
                const int bo = (nt * 16 + n16) * 72 + kc * 32 + qd * 8;
                short8 bh = *(const short8*)&Sxh[bo];
                short8 bl = *(const short8*)&Sxl[bo];
                aq[nt] = MFMA16(a1h, bh, aq[nt]);
                aq[nt] = MFMA16(a1h, bl, aq[nt]);
                aq[nt] = MFMA16(a1l, bh, aq[nt]);
                ak[nt] = MFMA16(a2h, bh, ak[nt]);
                ak[nt] = MFMA16(a2h, bl, ak[nt]);
                ak[nt] = MFMA16(a2l, bh, ak[nt]);
            }
        }
    }
#pragma unroll
    for (int nt = 0; nt < 4; ++nt) {
        int l = l0 + nt * 16 + n16;
        uint2 pq, pk;
        pq.x = f2bfu(aq[nt][0]) | (f2bfu(aq[nt][1]) << 16);
        pq.y = f2bfu(aq[nt][2]) | (f2bfu(aq[nt][3]) << 16);
        pk.x = f2bfu(ak[nt][0]) | (f2bfu(ak[nt][1]) << 16);
        pk.y = f2bfu(ak[nt][2]) | (f2bfu(ak[nt][3]) << 16);
        *(uint2*)(Qt + ((size_t)(b * 2048) + l) * 64 + w * 16 + qd * 4) = pq;
        *(uint2*)(Kt + ((size_t)(b * 2048) + l) * 64 + w * 16 + qd * 4) = pk;
    }
}

// ---------------------------------------------------------------------------
// K2: x -> XT (b, iblk, c, 64) bf16, 16B-chunk XOR-swizzled (key = c&7).
// grid (32 i-tiles, 8 c-tiles, 8 b), block 256.
// ---------------------------------------------------------------------------
__global__ __launch_bounds__(256) void xcvt_kernel(
    const float* __restrict__ x, b16u* __restrict__ XT)
{
    const int b = blockIdx.z, c0 = blockIdx.y * 64, it = blockIdx.x;
    const int tid = threadIdx.x;
#pragma unroll
    for (int p = 0; p < 4; ++p) {
        int flat = tid + p * 256;                 // 0..1023: 64 c x 16 groups
        int c = flat >> 4, s = flat & 15;
        float4 v = *(const float4*)(x + ((size_t)(b * 512) + c0 + c) * 2048 + it * 64 + s * 4);
        uint2 wv;
        wv.x = f2bfu(v.x) | (f2bfu(v.y) << 16);
        wv.y = f2bfu(v.z) | (f2bfu(v.w) << 16);
        int phys = (((s >> 1) ^ (c & 7)) << 3) + ((s & 1) << 2);   // shorts
        *(uint2*)(XT + (((size_t)(b * 32) + it) * 512 + c0 + c) * 64 + phys) = wv;
    }
}

// ---------------------------------------------------------------------------
// K3: P (swizzled (pb, iblk, j, 64)) = bf16(exp(S-20)), Zpart = row sums.
// S^T orientation: A=K (i rows), B=Q (j cols) -> lane holds 4 consecutive i
// at fixed j -> ds_write_b64 staging.  grid (2 i-halves, 32 j-tiles, nb).
// ---------------------------------------------------------------------------
__global__ __launch_bounds__(256) void pexp_kernel(
    const b16u* __restrict__ Qt, const b16u* __restrict__ Kt,
    b16u* __restrict__ P, float* __restrict__ Zpart, int b_off)
{
    __shared__ b16u Ks[64 * 72];    // [i][t]
    __shared__ b16u Ls[64 * 68];    // [j][i] staging
    __shared__ float Zw[4][64];
    const int pb = blockIdx.z, b = b_off + pb;
    const int j0 = blockIdx.y * 64;
    const int ibase = blockIdx.x * 1024;
    const int tid = threadIdx.x;
    const int lane = tid & 63;
    const int w = tid >> 6;
    const int n16 = lane & 15;
    const int qd = lane >> 4;
    const b16u* kb = Kt + (size_t)b * (2048 * 64);

    short8 qf[4][2];                // Q B-fragments, loop-invariant
#pragma unroll
    for (int nt = 0; nt < 4; ++nt)
#pragma unroll
        for (int kc = 0; kc < 2; ++kc)
            qf[nt][kc] = *(const short8*)(Qt +
                ((size_t)(b * 2048) + j0 + nt * 16 + n16) * 64 + kc * 32 + qd * 8);

    uint4 kreg[2];
#pragma unroll
    for (int p = 0; p < 2; ++p) {
        int flat = tid + p * 256;
        kreg[p] = *(const uint4*)(kb + (size_t)(ibase + (flat >> 3)) * 64 + (flat & 7) * 8);
    }
    float zacc[4] = {0.f, 0.f, 0.f, 0.f};

    for (int it = 0; it < 16; ++it) {
#pragma unroll
        for (int p = 0; p < 2; ++p) {
            int flat = tid + p * 256;
            *(uint4*)&Ks[(flat >> 3) * 72 + (flat & 7) * 8] = kreg[p];
        }
        {
            const int itn = (it + 1 < 16) ? it + 1 : 15;
#pragma unroll
            for (int p = 0; p < 2; ++p) {
                int flat = tid + p * 256;
                kreg[p] = *(const uint4*)(kb +
                    (size_t)(ibase + itn * 64 + (flat >> 3)) * 64 + (flat & 7) * 8);
            }
        }
        __syncthreads();
        floatx4 sacc[4];
#pragma unroll
        for (int nt = 0; nt < 4; ++nt) sacc[nt] = (floatx4){0.f, 0.f, 0.f, 0.f};
#pragma unroll
        for (int kc = 0; kc < 2; ++kc) {
            short8 af = *(const short8*)&Ks[(w * 16 + n16) * 72 + kc * 32 + qd * 8];
#pragma unroll
            for (int nt = 0; nt < 4; ++nt)
                sacc[nt] = MFMA16(af, qf[nt][kc], sacc[nt]);
        }
        // lane: j = j0+nt*16+n16 (col), i-local = w*16+qd*4+r (row)
#pragma unroll
        for (int nt = 0; nt < 4; ++nt) {
            float p0 = __expf(sacc[nt][0] - 20.0f);
            float p1 = __expf(sacc[nt][1] - 20.0f);
            float p2 = __expf(sacc[nt][2] - 20.0f);
            float p3 = __expf(sacc[nt][3] - 20.0f);
            zacc[nt] += (p0 + p1) + (p2 + p3);
            uint2 pk;
            pk.x = f2bfu(p0) | (f2bfu(p1) << 16);
            pk.y = f2bfu(p2) | (f2bfu(p3) << 16);
            *(uint2*)&Ls[(nt * 16 + n16) * 68 + w * 16 + qd * 4] = pk;
        }
        __syncthreads();
        // coalesced swizzled P write: 64 rows (j) x 128 B
        size_t prow = ((size_t)(pb * 32) + (ibase >> 6) + it) * 2048 + j0;
#pragma unroll
        for (int p = 0; p < 4; ++p) {
            int u = tid + p * 256;
            int row = u >> 4, s = u & 15;
            int phys = (((s >> 1) ^ (row & 7)) << 3) + ((s & 1) << 2);
            *(uint2*)(P + (prow + row) * 64 + phys) = *(const uint2*)&Ls[row * 68 + s * 4];
        }
    }
    // z: reduce over qd (i within wave), then over waves via LDS
#pragma unroll
    for (int nt = 0; nt < 4; ++nt) {
        float z = zacc[nt];
        z += __shfl_xor(z, 16);
        z += __shfl_xor(z, 32);
        if (qd == 0) Zw[w][nt * 16 + n16] = z;
    }
    __syncthreads();
    if (tid < 64) {
        float s = Zw[0][tid] + Zw[1][tid] + Zw[2][tid] + Zw[3][tid];
        Zpart[((size_t)blockIdx.x * 8 + b) * 2048 + j0 + tid] = s;
    }
}

// ---------------------------------------------------------------------------
// K4: out = x + gamma * zinv * (XT @ P^T).  M=512(c) N=2048(j) K=2048(i).
// Both operands bf16, pre-swizzled; staged via global_load_lds (16B) into
// unpadded double-buffered LDS; 1 barrier/iter; LDS-staged coalesced epilogue.
// grid (16 j, 4 c, nb), block 256; wave = 64c x 64j quadrant.
// ---------------------------------------------------------------------------
__global__ __launch_bounds__(256, 2) void gemm_kernel(
    const float* __restrict__ x, const b16u* __restrict__ XT,
    const b16u* __restrict__ P, const float* __restrict__ Zpart,
    const float* __restrict__ gamma, float* __restrict__ out, int b_off)
{
    __shared__ __align__(16) char smem[69632];
    b16u* As = (b16u*)smem;               // [2][8192] shorts
    b16u* Bs = (b16u*)(smem + 32768);     // [2][8192]
    const int pb = blockIdx.z, b = b_off + pb;
    const int j0 = blockIdx.x * 128;
    const int c0 = blockIdx.y * 128;
    const int tid = threadIdx.x;
    const int lane = tid & 63;
    const int w = tid >> 6;
    const int n16 = lane & 15;
    const int qd = lane >> 4;
    const int wc = w & 1;
    const int wj = w >> 1;

    const b16u* tA = XT + ((size_t)(b * 32) * 512 + c0) * 64 + w * 2048 + lane * 8;
    const b16u* tB = P + ((size_t)(pb * 32) * 2048 + j0) * 64 + w * 2048 + lane * 8;
    b16u* lA = As + w * 2048;
    b16u* lB = Bs + w * 2048;

#define STAGE(IT, BUF)                                                    \
    {                                                                      \
        const b16u* ga = tA + (size_t)(IT) * 32768;                        \
        const b16u* gb = tB + (size_t)(IT) * 131072;                       \
        _Pragma("unroll")                                                  \
        for (int ch = 0; ch < 4; ++ch) {                                   \
            gl2lds16(ga + ch * 512, lA + (BUF) * 8192 + ch * 512);         \
            gl2lds16(gb + ch * 512, lB + (BUF) * 8192 + ch * 512);         \
        }                                                                  \
    }

    STAGE(0, 0)
    __syncthreads();

    floatx4 acc[4][4];
#pragma unroll
    for (int mt = 0; mt < 4; ++mt)
#pragma unroll
        for (int nt = 0; nt < 4; ++nt) acc[mt][nt] = (floatx4){0.f, 0.f, 0.f, 0.f};

    for (int it = 0; it < 32; ++it) {
        const int buf = it & 1;
        if (it < 31) STAGE(it + 1, buf ^ 1)
        const b16u* Ab = As + buf * 8192;
        const b16u* Bb = Bs + buf * 8192;
#pragma unroll
        for (int kc = 0; kc < 2; ++kc) {
            const int co = (((kc * 4 + qd) ^ (n16 & 7)) << 3);   // phys chunk offset
            short8 af[4], bf[4];
#pragma unroll
            for (int mt = 0; mt < 4; ++mt)
                af[mt] = *(const short8*)&Ab[(wc * 64 + mt * 16 + n16) * 64 + co];
#pragma unroll
            for (int nt = 0; nt < 4; ++nt)
                bf[nt] = *(const short8*)&Bb[(wj * 64 + nt * 16 + n16) * 64 + co];
#pragma unroll
            for (int mt = 0; mt < 4; ++mt)
#pragma unroll
                for (int nt = 0; nt < 4; ++nt)
                    acc[mt][nt] = MFMA16(af[mt], bf[nt], acc[mt][nt]);
        }
        __syncthreads();
    }
#undef STAGE

    // ---- epilogue: scale by g*zinv, stage per-wave quadrant, coalesced out ----
    const float g = gamma[0];
    float* st = (float*)(smem + w * 17408);       // 64 x 68 floats per wave
#pragma unroll
    for (int nt = 0; nt < 4; ++nt) {
        int j = j0 + wj * 64 + nt * 16 + n16;
        float zi = g / (Zpart[(size_t)b * 2048 + j] +
                        Zpart[16384 + (size_t)b * 2048 + j]);
#pragma unroll
        for (int mt = 0; mt < 4; ++mt)
#pragma unroll
            for (int r = 0; r < 4; ++r)
                st[(mt * 16 + qd * 4 + r) * 68 + nt * 16 + n16] = acc[mt][nt][r] * zi;
    }
    __syncthreads();
#pragma unroll
    for (int p = 0; p < 16; ++p) {
        int rl = qd * 16 + p;                     // c-local row in quadrant
        int cg = c0 + wc * 64 + rl;
        size_t go = ((size_t)(b * 512) + cg) * 2048 + j0 + wj * 64 + n16 * 4;
        float4 v = *(const float4*)&st[rl * 68 + n16 * 4];
        float4 xv = *(const float4*)(x + go);
        v.x += xv.x; v.y += xv.y; v.z += xv.z; v.w += xv.w;
        *(float4*)(out + go) = v;
    }
}

// ---------------------------------------------------------------------------
extern "C" void kernel_launch(void* const* d_in, const int* in_sizes, int n_in,
                              void* d_out, int out_size, void* d_ws, size_t ws_size,
                              hipStream_t stream)
{
    const float* x     = (const float*)d_in[0];
    const float* W1    = (const float*)d_in[1];
    const float* W2    = (const float*)d_in[2];
    const float* gamma = (const float*)d_in[3];
    float* out = (float*)d_out;

    b16u* Qt  = (b16u*)d_ws;                        // 2 MB
    b16u* Kt  = Qt  + (size_t)BB * LL * TT;         // 2 MB
    b16u* W1h = Kt  + (size_t)BB * LL * TT;         // 64 KB x4
    b16u* W1l = W1h + (size_t)TT * CC;
    b16u* W2h = W1l + (size_t)TT * CC;
    b16u* W2l = W2h + (size_t)TT * CC;
    float* Zp = (float*)(W2l + (size_t)TT * CC);    // 128 KB
    b16u* XT  = (b16u*)(Zp + 2 * 8 * 2048);         // 16.8 MB
    b16u* P   = XT + (size_t)BB * 32 * 512 * 64;    // nb * 8.39 MB

    const size_t base = (size_t)((char*)P - (char*)d_ws);
    const size_t pbat = (size_t)LL * LL * 2;
    int nb = 8;
    if (ws_size < base + 8 * pbat) nb = 4;
    if (ws_size < base + 4 * pbat) nb = 2;
    if (ws_size < base + 2 * pbat) nb = 1;

    wcvt_kernel <<<dim3(32),        256, 0, stream>>>(W1, W2, W1h, W1l, W2h, W2l);
    qkcvt_kernel<<<dim3(32, BB),    256, 0, stream>>>(x, W1h, W1l, W2h, W2l, Qt, Kt);
    xcvt_kernel <<<dim3(32, 8, BB), 256, 0, stream>>>(x, XT);
    for (int b0 = 0; b0 < BB; b0 += nb) {
        pexp_kernel<<<dim3(2, 32, nb), 256, 0, stream>>>(Qt, Kt, P, Zp, b0);
        gemm_kernel<<<dim3(16, 4, nb), 256, 0, stream>>>(x, XT, P, Zp, gamma, out, b0);
    }
}